// Round 10
// baseline (94.013 us; speedup 1.0000x reference)
//
#include <hip/hip_runtime.h>
#include <hip/hip_fp16.h>
#include <math.h>

#define HH 512
#define WW 512
#define BB 4
#define NCLS 20
#define NINST 32
#define NPIX (HH*WW)
#define NCH 24
#define NBIN 128                // bins over err/2 in [0,1]; err bin width 1/64
#define NCHUNK3 256
#define CPX3 1024               // pixels per K3 block
#define K3T 512
#define HSTR 33                 // hc row stride (u32): bank(bin*33+j)%32=(bin+j)%32

// ---- workspace layout (bytes) ----
#define OFF_PARTA  ((size_t)0)                       // float[1024 blocks][8f*32j] = 1MB
#define OFF_PSEED  (OFF_PARTA + 1024*256*4)          // float[1024]
#define OFF_STATS  (OFF_PSEED + 1024*4)              // float[8][128]
#define OFF_DER    (OFF_STATS + 8*128*4)             // float[7][128]
#define OFF_SEEDBG (OFF_DER + 7*128*4)               // float[4]
#define OFF_INSTL  (OFF_SEEDBG + 4*4)                // float[128]
#define OFF_SFG    (OFF_INSTL + 128*4)               // float[1024]
#define OFF_REC    ((OFF_SFG + 1024*4 + 255) & ~(size_t)255)  // uint2[B][NPIX] = 8MB
#define OFF_HIST   (OFF_REC + (size_t)BB*NPIX*8)     // u32[B][256][32][128] = 16MB

__device__ __forceinline__ float fast_rcp(float x) { return __builtin_amdgcn_rcpf(x); }
__device__ __forceinline__ float fast_sigmoid(float z) { return fast_rcp(1.0f + __expf(-z)); }
__device__ __forceinline__ float fast_tanh(float x) {
  return 1.0f - 2.0f * fast_rcp(__expf(2.0f * x) + 1.0f);
}

// K1: 1024 blocks (256/image), 4 px/thread. Per-pixel stats to per-block
// partials (NO global atomics), seed_bg partial, 8-byte rec for K3.
__global__ __launch_bounds__(256) void k1_stats(
    const float* __restrict__ pred, const int* __restrict__ inst,
    const int* __restrict__ lab,
    float* __restrict__ partA, float* __restrict__ partSeed,
    uint2* __restrict__ rec)
{
  __shared__ unsigned s_st[4][NINST][9];  // [0]=cnt|G<<16, [1..6]=float bits
  __shared__ float s_seed;
  int t = threadIdx.x;
  int w = t >> 6;
  for (int i = t; i < 4*NINST*9; i += 256) ((unsigned*)s_st)[i] = 0u;
  if (t == 0) s_seed = 0.f;
  __syncthreads();

  int b = blockIdx.x >> 8;
  int blk = blockIdx.x & 255;
  const float* pb = pred + (size_t)b*NCH*NPIX;
  float seedloc = 0.f;

  int p = blk*1024 + t*4;
  float4 e0v = *(const float4*)(pb + p);
  float4 e1v = *(const float4*)(pb + NPIX + p);
  float4 g0v = *(const float4*)(pb + 2*NPIX + p);
  float4 g1v = *(const float4*)(pb + 3*NPIX + p);
  int4 idv = *(const int4*)(inst + (size_t)b*NPIX + p);
  int4 lbv = *(const int4*)(lab + (size_t)b*NPIX + p);

  #pragma unroll
  for (int u = 0; u < 4; ++u) {
    int px = p + u;
    int x = px & (WW-1);
    int y = px >> 9;
    float xm = x * (1.0f/(WW-1));
    float ym = y * (1.0f/(HH-1));
    float g0 = (&g0v.x)[u];
    float g1 = (&g1v.x)[u];
    int id = (&idv.x)[u];
    int lb = (&lbv.x)[u];
    if (id >= 1) {
      int j = id - 1;
      unsigned* row = s_st[w][j];
      atomicAdd(&row[0], 1u | ((lb != 255) ? 0x10000u : 0u));
      atomicAdd((float*)&row[1], xm);
      atomicAdd((float*)&row[2], ym);
      atomicAdd((float*)&row[3], g0);
      atomicAdd((float*)&row[4], g1);
      atomicAdd((float*)&row[5], g0*g0);
      atomicAdd((float*)&row[6], g1*g1);
    }
  }

  float so[4] = {0.f,0.f,0.f,0.f};
  float Sv[4] = {0.f,0.f,0.f,0.f};
  for (int c = 0; c < NCLS; ++c) {
    float4 sv = *(const float4*)(pb + (size_t)(4+c)*NPIX + p);
    #pragma unroll
    for (int u = 0; u < 4; ++u) {
      float sg = fast_sigmoid((&sv.x)[u]);
      Sv[u] += sg*sg;
      if (c + 1 == (&lbv.x)[u]) so[u] = sg;
    }
  }
  #pragma unroll
  for (int u = 0; u < 4; ++u)
    if ((&lbv.x)[u] != 255) seedloc += Sv[u] - so[u]*so[u];

  // rec: {f16 ex, f16 ey, u8 sg_own, u8 (id | valid<<7)}
  {
    uint2 r4[4];
    #pragma unroll
    for (int u = 0; u < 4; ++u) {
      int px = p + u;
      int x = px & (WW-1);
      int y = px >> 9;
      float ex = fast_tanh((&e0v.x)[u]) + x * (1.0f/(WW-1));
      float ey = fast_tanh((&e1v.x)[u]) + y * (1.0f/(HH-1));
      __half2 h = __floats2half2_rn(ex, ey);
      unsigned valid = ((&lbv.x)[u] != 255) ? 1u : 0u;
      unsigned meta = (unsigned)(&idv.x)[u] | (valid << 7);
      r4[u].x = *reinterpret_cast<unsigned*>(&h);
      r4[u].y = (unsigned)(unsigned char)(so[u]*255.f + 0.5f) | (meta << 8);
    }
    uint4* dst = (uint4*)(rec + (size_t)b*NPIX + p);
    dst[0] = make_uint4(r4[0].x, r4[0].y, r4[1].x, r4[1].y);
    dst[1] = make_uint4(r4[2].x, r4[2].y, r4[3].x, r4[3].y);
  }

  for (int o = 32; o; o >>= 1) seedloc += __shfl_down(seedloc, o);
  if ((t & 63) == 0) atomicAdd(&s_seed, seedloc);
  __syncthreads();

  {
    int j = t & 31, f = t >> 5;
    float v;
    if (f == 0) {
      unsigned s = (s_st[0][j][0] & 0xFFFFu) + (s_st[1][j][0] & 0xFFFFu)
                 + (s_st[2][j][0] & 0xFFFFu) + (s_st[3][j][0] & 0xFFFFu);
      v = (float)s;
    } else if (f == 7) {
      unsigned s = (s_st[0][j][0] >> 16) + (s_st[1][j][0] >> 16)
                 + (s_st[2][j][0] >> 16) + (s_st[3][j][0] >> 16);
      v = (float)s;
    } else {
      v = __uint_as_float(s_st[0][j][f]) + __uint_as_float(s_st[1][j][f])
        + __uint_as_float(s_st[2][j][f]) + __uint_as_float(s_st[3][j][f]);
    }
    partA[(blockIdx.x << 8) + t] = v;
  }
  if (t == 0) partSeed[blockIdx.x] = s_seed;
}

// K2a: parallel partial reduction. 32 blocks = (image, field).
__global__ __launch_bounds__(256) void k2a_reduce(
    const float* __restrict__ partA, float* __restrict__ stats)
{
  __shared__ float red[256];
  int bid = blockIdx.x;                   // b*8 + f
  int b = bid >> 3, f = bid & 7;
  int t = threadIdx.x;
  int j = t & 31, grp = t >> 5;           // 8 groups of 32 blocks each
  float s = 0.f;
  #pragma unroll 8
  for (int k = 0; k < 32; ++k) {
    int blk = grp*32 + k;
    s += partA[((b*256 + blk) << 8) + (f << 5) + j];
  }
  red[t] = s; __syncthreads();
  for (int st = 128; st >= 32; st >>= 1) {
    if (t < st) red[t] += red[t + st];
    __syncthreads();
  }
  if (t < 32) stats[f*128 + b*32 + t] = red[t];
}

// K2b: derive per-pair constants + seed_bg reduce. One tiny block.
__global__ __launch_bounds__(128) void k2b_derive(
    const float* __restrict__ stats, const float* __restrict__ partSeed,
    float* __restrict__ der, float* __restrict__ seedbg)
{
  int t = threadIdx.x;                    // 128
  if (t < 4) {
    float ss = 0.f;
    for (int i = 0; i < 256; ++i) ss += partSeed[t*256 + i];
    seedbg[t] = ss;
  }
  float cntA = stats[0*128+t];
  float cnt = fmaxf(cntA, 1.0f);
  float sumx = stats[1*128+t], sumy = stats[2*128+t];
  float s0 = stats[3*128+t], s1 = stats[4*128+t];
  float q0 = stats[5*128+t], q1 = stats[6*128+t];
  float Gv = stats[7*128+t];
  float cx = sumx/cnt, cy = sumy/cnt;
  float sm0 = s0/cnt, sm1 = s1/cnt;
  float varnum = q0 - 2.f*sm0*s0 + cntA*sm0*sm0
               + q1 - 2.f*sm1*s1 + cntA*sm1*sm1;
  float varl = varnum / (2.0f * cnt);
  der[0*128+t] = cx;
  der[1*128+t] = cy;
  der[2*128+t] = -1.442695041f * expf(10.f*sm0);  // pre-scaled for exp2
  der[3*128+t] = -1.442695041f * expf(10.f*sm1);
  der[4*128+t] = varl;
  der[5*128+t] = Gv;
}

// K3: block = (image, 1024-px chunk); 8 waves; lane = (px-slot<<5)|instance.
// hc[bin*33 + inst] -> atomic bank = (bin+inst)%32: conflict-free by design.
__global__ __launch_bounds__(K3T) void k3_hist(
    const uint2* __restrict__ rec, const float* __restrict__ der,
    unsigned* __restrict__ hist, float* __restrict__ sfg)
{
  __shared__ unsigned hc[NBIN*HSTR];      // 16.9 KB
  __shared__ float s_fg[8];
  int t = threadIdx.x;
  for (int i = t; i < NBIN*HSTR; i += K3T) hc[i] = 0u;
  int bid = blockIdx.x;                   // 1024
  int b = bid >> 8;
  int chunk = bid & 255;
  int w = t >> 6, lane = t & 63;
  int j = lane & 31, jp1 = j + 1;
  int pair = b*NINST + j;
  float cx = der[0*128+pair], cy = der[1*128+pair];
  float s0 = der[2*128+pair], s1 = der[3*128+pair];   // = -1.4427*exp(10 sm)
  const uint2* rb = rec + (size_t)b*NPIX + chunk*CPX3 + w*128;
  __syncthreads();

  float fg = 0.f;
  #pragma unroll 4
  for (int r = 0; r < 64; ++r) {
    uint2 rv = rb[r*2 + (lane >> 5)];
    __half2 h;
    *reinterpret_cast<unsigned*>(&h) = rv.x;
    float2 e = __half22float2(h);
    unsigned hi = rv.y;
    float dx = e.x - cx, dy = e.y - cy;
    float dist = exp2f(dx*dx*s0 + dy*dy*s1);
    bool own = ((int)((hi >> 8) & 0x3F) == jp1);
    if (own) { float d = (float)(hi & 0xFFu)*(1.0f/255.f) - dist; fg += d*d; }
    if (hi & 0x8000u) {
      float f = own ? (1.0f - dist) : dist;            // err/2 in [0,1]
      unsigned bin = min((unsigned)(f * (float)NBIN), NBIN-1u);
      atomicAdd(&hc[bin*HSTR + j], own ? 0x10001u : 1u);
    }
  }
  for (int o = 32; o; o >>= 1) fg += __shfl_down(fg, o);
  if (lane == 0) s_fg[w] = fg;
  __syncthreads();
  if (t == 0) {
    float s = 0.f;
    #pragma unroll
    for (int i = 0; i < 8; ++i) s += s_fg[i];
    sfg[bid] = 10.0f * s;                  // fg_w = 10
  }
  // transposed flush -> hist[b][chunk][inst][bin] (coalesced for K4)
  unsigned* out = hist + (size_t)(b*NCHUNK3 + chunk) * (NINST*NBIN);
  #pragma unroll
  for (int k = 0; k < NINST*NBIN/K3T; ++k) {
    int idx = k*K3T + t;
    out[idx] = hc[(idx & 127)*HSTR + (idx >> 7)];
  }
}

// K4: per pair: 4 groups reduce 64 chunks each (coalesced), combine, then
// one wave does the 128-bin descending Lovasz scan.
__global__ __launch_bounds__(512) void k4_scan(
    const unsigned* __restrict__ hist, const float* __restrict__ der,
    float* __restrict__ instl)
{
  __shared__ unsigned s_c[4][NBIN], s_p[4][NBIN];
  int t = threadIdx.x;
  int pair = blockIdx.x;
  int b = pair >> 5, j = pair & 31;
  int grp = t >> 7, bin = t & 127;
  const unsigned* bp = hist + ((size_t)b*NCHUNK3*NINST + j)*NBIN + bin;
  unsigned c = 0, p = 0;
  #pragma unroll 8
  for (int ch = grp*64; ch < grp*64 + 64; ++ch) {
    unsigned v = bp[(size_t)ch * (NINST*NBIN)];
    c += v & 0xFFFFu; p += v >> 16;
  }
  s_c[grp][bin] = c; s_p[grp][bin] = p;
  __syncthreads();
  if (t < NBIN) {
    s_c[0][t] += s_c[1][t] + s_c[2][t] + s_c[3][t];
    s_p[0][t] += s_p[1][t] + s_p[2][t] + s_p[3][t];
  }
  __syncthreads();

  if (t < 64) {
    int lane = t;
    float G = der[5*128+pair];
    unsigned carryN = 0, carryP = 0;
    float Jprev = 0.f, L = 0.f;
    for (int c8 = 0; c8 < NBIN/64; ++c8) {
      int k = NBIN - 1 - c8*64 - lane;
      unsigned n = s_c[0][k], pp0 = s_p[0][k];
      for (int off = 1; off < 64; off <<= 1) {
        unsigned nn = __shfl_up(n, off);
        unsigned pq = __shfl_up(pp0, off);
        if (lane >= off) { n += nn; pp0 += pq; }
      }
      float fN = (float)(carryN + n);
      float fP = (float)(carryP + pp0);
      float uni = G + fN - fP;
      float J = 1.0f - (G - fP) / fmaxf(uni, 1e-9f);
      float Jp = __shfl_up(J, 1);
      if (lane == 0) Jp = Jprev;
      float v = (k + 0.5f) * (2.0f/NBIN);
      L += v * (J - Jp);
      carryN += __shfl(n, 63);
      carryP += __shfl(pp0, 63);
      Jprev  = __shfl(J, 63);
    }
    for (int o = 32; o; o >>= 1) L += __shfl_down(L, o);
    if (lane == 0) instl[pair] = L;
  }
}

// K5: final combine.
__global__ __launch_bounds__(256) void k5_final(
    const float* __restrict__ instl, const float* __restrict__ der,
    const float* __restrict__ seedbg, const float* __restrict__ sfg,
    float* __restrict__ out)
{
  __shared__ float red[256];
  int t = threadIdx.x;
  float acc = 0.f;
  for (int i = t; i < 1024; i += 256) acc += sfg[i];
  acc *= (1.0f/NPIX);
  if (t < 4) acc += seedbg[t] * (1.0f/NPIX);
  if (t < 128) acc += (instl[t] + 10.0f*der[4*128+t]) * (1.0f/NINST);
  red[t] = acc; __syncthreads();
  for (int s = 128; s; s >>= 1) { if (t < s) red[t] += red[t+s]; __syncthreads(); }
  if (t == 0) out[0] = red[0] * (1.0f/BB);
}

extern "C" void kernel_launch(void* const* d_in, const int* in_sizes, int n_in,
                              void* d_out, int out_size, void* d_ws, size_t ws_size,
                              hipStream_t stream)
{
  const float* pred = (const float*)d_in[0];
  const int* inst = (const int*)d_in[1];
  const int* lab  = (const int*)d_in[2];
  char* ws = (char*)d_ws;
  float* partA = (float*)(ws + OFF_PARTA);
  float* partSeed = (float*)(ws + OFF_PSEED);
  float* stats = (float*)(ws + OFF_STATS);
  float* der = (float*)(ws + OFF_DER);
  float* seedbg = (float*)(ws + OFF_SEEDBG);
  float* instl = (float*)(ws + OFF_INSTL);
  float* sfg = (float*)(ws + OFF_SFG);
  uint2* rec = (uint2*)(ws + OFF_REC);
  unsigned* hist = (unsigned*)(ws + OFF_HIST);

  hipLaunchKernelGGL(k1_stats, dim3(1024), dim3(256), 0, stream,
                     pred, inst, lab, partA, partSeed, rec);
  hipLaunchKernelGGL(k2a_reduce, dim3(32), dim3(256), 0, stream, partA, stats);
  hipLaunchKernelGGL(k2b_derive, dim3(1), dim3(128), 0, stream,
                     stats, partSeed, der, seedbg);
  hipLaunchKernelGGL(k3_hist, dim3(BB*NCHUNK3), dim3(K3T), 0, stream,
                     rec, der, hist, sfg);
  hipLaunchKernelGGL(k4_scan, dim3(128), dim3(512), 0, stream, hist, der, instl);
  hipLaunchKernelGGL(k5_final, dim3(1), dim3(256), 0, stream,
                     instl, der, seedbg, sfg, (float*)d_out);
}